// Round 11
// baseline (163.068 us; speedup 1.0000x reference)
//
#include <hip/hip_runtime.h>
#include <math.h>

// ---------------------------------------------------------------------------
// PredictiveModule R11 = R9 pipeline + atomic-accumulated y (no partials).
//
// R10 lesson: per-block serial reduce prologues cost more than extra
// launches. R11 removes the reduction entirely: mv blocks unsafeAtomicAdd
// their f64 column partials into y[N] (native global_atomic_add_f64;
// <=128 spread-out contenders/address). mv2/mv3 prologue is then a SINGLE
// load: x = relu(y_prev[k] + bias[k]) -> ballot-compact nonzero rows ->
// unchanged R6/R9 pipeline (TR=8 rows x 1KB, wave-private LDS double
// buffers via global_load_lds, s_waitcnt vmcnt(8), no __syncthreads in
// the K-loop). 6 dispatches: memset(y) -> mv1 -> mv2 -> mv3 -> finalize
// -> topk.
//
// Numerics: f64 accumulation; atomic-order nondeterminism ~1e-13 vs ~3e-5
// top-k gaps (and a 519 absmax threshold). f32 rounding only at
// sample = f32(am) + 0.05f*noise. Top-k ties stable by ascending index.
// ---------------------------------------------------------------------------

constexpr int D = 16384;
constexpr int H = 4096;

__device__ __forceinline__ void stage16(const float* g, const float* l) {
    __builtin_amdgcn_global_load_lds(
        (const __attribute__((address_space(1))) unsigned int*)g,
        (__attribute__((address_space(3))) unsigned int*)l,
        16, 0, 0);
}

__device__ __forceinline__ double wredsum(double v) {
    #pragma unroll
    for (int o = 32; o > 0; o >>= 1) v += __shfl_down(v, o, 64);
    return v;
}

// Split-K matvec: grid (N/1024, K/KC). Block: 256 thr / 4 waves; wave w owns
// cols [bx*1024 + w*256, +256). FRED: x = relu(yprev[k]+bias[k]) (1 load),
// ballot-compact nonzero rows, stage only those. Epilogue: f64 atomicAdd
// into yout[col].
template<int KC, bool FRED>
__global__ __launch_bounds__(256) void k_mv(
    const float* __restrict__ W, int N,
    const float* __restrict__ xf,          // !FRED: dense f32 x (mv1: ct)
    const double* __restrict__ yprev,      // FRED: accumulated prev y (f64)
    const float* __restrict__ bias,        // FRED: bias for relu
    double* __restrict__ yout)             // f64, atomically accumulated
{
    constexpr int NWC = (KC + 63) / 64;    // waves covering t < KC
    __shared__ float wbuf[4][2][8][256];   // 64 KB wave-private double buffers
    __shared__ double xv[KC];
    __shared__ int cidx[KC];
    __shared__ int wtot[NWC > 0 ? NWC : 1];
    __shared__ int s_nt;

    const int t = threadIdx.x, lane = t & 63, w = t >> 6;
    const int k0 = blockIdx.y * KC;

    if constexpr (!FRED) {
        if (t < KC) { xv[t] = (double)xf[k0 + t]; cidx[t] = t; }
        if (t == 0) s_nt = KC / 8;
    } else {
        double x = 0.0; bool pred = false;
        if (t < KC) {
            const double v = yprev[k0 + t] + (double)bias[k0 + t];
            x = v > 0.0 ? v : 0.0;                   // relu
            pred = x > 0.0;
        }
        // order-preserving ballot compaction of nonzero rows
        const unsigned long long mask = __ballot(pred);
        const int rank = __popcll(mask & ((1ull << lane) - 1ull));
        const int tot  = __popcll(mask);
        if (t < KC && lane == 0) wtot[t >> 6] = tot;
        __syncthreads();
        int woffs = 0;
        #pragma unroll
        for (int ww = 0; ww < NWC; ++ww)
            if (ww < (t >> 6)) woffs += wtot[ww];
        if (pred) { cidx[woffs + rank] = t; xv[woffs + rank] = x; }
        int m = 0;
        #pragma unroll
        for (int ww = 0; ww < NWC; ++ww) m += wtot[ww];
        const int m8 = (m + 7) & ~7;
        __syncthreads();                    // compacted writes visible
        if (t >= m && t < m8) { cidx[t] = 0; xv[t] = 0.0; }  // pad (x=0)
        if (t == 0) s_nt = m8 / 8;
    }
    __syncthreads();
    const int nt = s_nt;

    const int cbase = blockIdx.x * 1024 + w * 256;
    const float* Wg = W + (size_t)k0 * N + cbase + lane * 4;
    float* b0 = &wbuf[w][0][0][0];
    float* b1 = &wbuf[w][1][0][0];
    double a0 = 0, a1 = 0, a2 = 0, a3 = 0;

    if (nt > 0) {
        #pragma unroll
        for (int r = 0; r < 8; ++r)                     // stage tile 0
            stage16(Wg + (size_t)cidx[r] * N, b0 + r * 256);

        for (int tt = 0; tt < nt; ++tt) {
            if (tt + 1 < nt) {
                const int j = (tt + 1) * 8;
                #pragma unroll
                for (int r = 0; r < 8; ++r)             // stage tile tt+1
                    stage16(Wg + (size_t)cidx[j + r] * N, b1 + r * 256);
                asm volatile("s_waitcnt vmcnt(8)" ::: "memory");  // tt landed
            } else {
                asm volatile("s_waitcnt vmcnt(0)" ::: "memory");
            }
            #pragma unroll
            for (int r = 0; r < 8; ++r) {               // consume tile tt
                const float4 wv = *reinterpret_cast<const float4*>(b0 + r * 256 + lane * 4);
                const double x = xv[tt * 8 + r];
                a0 += x * (double)wv.x; a1 += x * (double)wv.y;
                a2 += x * (double)wv.z; a3 += x * (double)wv.w;
            }
            float* tmp = b0; b0 = b1; b1 = tmp;
        }
    }

    // epilogue: accumulate into y (fire-and-forget device atomics)
    const int c = cbase + lane * 4;
    unsafeAtomicAdd(&yout[c + 0], a0);
    unsafeAtomicAdd(&yout[c + 1], a1);
    unsafeAtomicAdd(&yout[c + 2], a2);
    unsafeAtomicAdd(&yout[c + 3], a3);
}

// vm = clip(y3[i]+b3, +-100); gate = sigmoid(qm*ct); am = clip(gate*vm,
// +-1000); sample = f32(am)+0.05f*noise; per-block logprob partial.
__global__ __launch_bounds__(256) void k_finalize(
    const double* __restrict__ y3,
    const float* __restrict__ b3,
    const float* __restrict__ qm,
    const float* __restrict__ ct,
    const float* __restrict__ noise,
    float* __restrict__ samp,
    double* __restrict__ lpp)
{
    const int i = blockIdx.x * 256 + threadIdx.x;
    double vm = y3[i] + (double)b3[i];
    vm = vm > 100.0 ? 100.0 : (vm < -100.0 ? -100.0 : vm);
    const double z = (double)qm[i] * (double)ct[i];
    const double g = 1.0 / (1.0 + exp(-z));
    double am = g * vm;                          // influence == 1.0
    am = am > 1000.0 ? 1000.0 : (am < -1000.0 ? -1000.0 : am);
    const float amf = (float)am;
    const float sp = amf + 0.05f * noise[i];
    samp[i] = sp;
    const float df = (sp - amf) / 0.05f;
    double term = (double)df * (double)df;
    term = wredsum(term);
    __shared__ double red[4];
    const int lane = threadIdx.x & 63, wid = threadIdx.x >> 6;
    if (lane == 0) red[wid] = term;
    __syncthreads();
    if (threadIdx.x == 0) lpp[blockIdx.x] = red[0] + red[1] + red[2] + red[3];
}

// Single-block radix-select top-k (stable ties by index) + final writes.
#define TPK 1024
__global__ __launch_bounds__(TPK) void k_topk(
    const float* __restrict__ samp,
    const int* __restrict__ kptr,
    const double* __restrict__ lpp, int GLP,
    float* __restrict__ out)
{
    __shared__ unsigned int u[16384];
    __shared__ int whist[16][257];
    __shared__ int hist[256];
    __shared__ int sfx[256];
    __shared__ int wsum[16];
    __shared__ int wcnt[4];
    __shared__ unsigned int s_prefix;
    __shared__ int s_kk;

    const int t = threadIdx.x;
    const int lane = t & 63, wid = t >> 6;

    for (int i = t; i < D; i += TPK)
        u[i] = __float_as_uint(samp[i]) & 0x7fffffffu;
    __syncthreads();

    const int k = *kptr;
    unsigned int prefix = 0;
    int kk = k;
    for (int pass = 0; pass < 4; ++pass) {
        const int shift = 24 - 8 * pass;
        const unsigned int dm = pass ? (0xffffffffu << (32 - 8 * pass)) : 0u;
        for (int i = t; i < 16 * 257; i += TPK) (&whist[0][0])[i] = 0;
        __syncthreads();
        for (int i = t; i < D; i += TPK) {
            const unsigned int v = u[i];
            if ((v & dm) == prefix)
                atomicAdd(&whist[wid][(v >> shift) & 0xff], 1);
        }
        __syncthreads();
        if (t < 256) {
            int s = 0;
            #pragma unroll
            for (int w = 0; w < 16; ++w) s += whist[w][t];
            hist[t] = s;
            sfx[t] = s;
        }
        __syncthreads();
        #pragma unroll
        for (int off = 1; off < 256; off <<= 1) {
            int add = 0;
            if (t < 256 && t + off < 256) add = sfx[t + off];
            __syncthreads();
            if (t < 256) sfx[t] += add;
            __syncthreads();
        }
        const bool cond = (t < 256) && (sfx[t] >= kk);
        const unsigned long long m = __ballot(cond);
        if (lane == 0 && wid < 4) wcnt[wid] = __popcll(m);
        __syncthreads();
        if (t == 0) {
            const int bs = wcnt[0] + wcnt[1] + wcnt[2] + wcnt[3] - 1;
            s_kk = kk - (sfx[bs] - hist[bs]);
            s_prefix = prefix | ((unsigned int)bs << shift);
        }
        __syncthreads();
        prefix = s_prefix;
        kk = s_kk;
        __syncthreads();
    }
    const unsigned int vstar = prefix;
    const int need = kk;

    constexpr int PER = D / TPK;  // 16
    const int base = t * PER;
    float vals[PER];
    unsigned int keys[PER];
    int cnt = 0;
    #pragma unroll
    for (int j = 0; j < PER; ++j) {
        const float f = samp[base + j];
        vals[j] = f;
        keys[j] = __float_as_uint(f) & 0x7fffffffu;
        cnt += (keys[j] == vstar) ? 1 : 0;
    }
    int inc = cnt;
    #pragma unroll
    for (int o = 1; o < 64; o <<= 1) {
        const int n = __shfl_up(inc, o, 64);
        if (lane >= o) inc += n;
    }
    if (lane == 63) wsum[wid] = inc;
    __syncthreads();
    int woff = 0;
    for (int w = 0; w < wid; ++w) woff += wsum[w];
    int offset = woff + inc - cnt;
    #pragma unroll
    for (int j = 0; j < PER; ++j) {
        float o2 = 0.0f;
        if (keys[j] > vstar) {
            o2 = vals[j];
        } else if (keys[j] == vstar) {
            if (offset < need) o2 = vals[j];
            offset++;
        }
        out[base + j] = o2;
    }

    if (wid == 0) {
        double s = 0;
        for (int g = lane; g < GLP; g += 64) s += lpp[g];
        s = wredsum(s);
        if (lane == 0) {
            const double c = -log(0.05) - 0.5 * log(2.0 * 3.14159265358979323846);
            out[D] = (float)(-0.5 * s + (double)D * c);
        }
    }
}

extern "C" void kernel_launch(void* const* d_in, const int* in_sizes, int n_in,
                              void* d_out, int out_size, void* d_ws, size_t ws_size,
                              hipStream_t stream) {
    const float* ct    = (const float*)d_in[0];
    const float* W1    = (const float*)d_in[1];
    const float* b1    = (const float*)d_in[2];
    const float* W2    = (const float*)d_in[3];
    const float* b2    = (const float*)d_in[4];
    const float* W3    = (const float*)d_in[5];
    const float* b3    = (const float*)d_in[6];
    const float* qm    = (const float*)d_in[7];
    const float* noise = (const float*)d_in[8];
    const int*   kp    = (const int*)d_in[9];

    // R9 geometry: 512-block matvec grids (2 blocks/CU at ~66KB LDS)
    constexpr int KC1 = 128, KC2 = 32, KC3 = 128;
    constexpr int G1 = D / KC1;   // 128
    constexpr int GLP = D / 256;  // 64
    (void)G1;

    // ws: y1[H] | y2[H] | y3[D] (f64, zeroed) | samp[D] f32 | lpp[GLP]
    double* y1   = (double*)d_ws;
    double* y2   = y1 + H;
    double* y3   = y2 + H;
    float*  samp = (float*)(y3 + D);
    double* lpp  = (double*)(samp + D);

    hipMemsetAsync(d_ws, 0, (size_t)(2 * H + D) * 8, stream);  // y = +0.0

    // mv1: K=D, N=H, x = ct
    k_mv<KC1, false><<<dim3(H / 1024, D / KC1), 256, 0, stream>>>(
        W1, H, ct, nullptr, nullptr, y1);
    // mv2: K=H, N=H, x = relu(y1+b1), row-skip
    k_mv<KC2, true><<<dim3(H / 1024, H / KC2), 256, 0, stream>>>(
        W2, H, nullptr, y1, b1, y2);
    // mv3: K=H, N=D, x = relu(y2+b2), row-skip
    k_mv<KC3, true><<<dim3(D / 1024, H / KC3), 256, 0, stream>>>(
        W3, D, nullptr, y2, b2, y3);
    // finalize: elementwise + logprob partials
    k_finalize<<<dim3(D / 256), 256, 0, stream>>>(
        y3, b3, qm, ct, noise, samp, lpp);
    // topk: select + write all outputs
    k_topk<<<dim3(1), TPK, 0, stream>>>(samp, kp, lpp, GLP, (float*)d_out);
}

// Round 12
// 136.848 us; speedup vs baseline: 1.1916x; 1.1916x over previous
//
#include <hip/hip_runtime.h>
#include <math.h>

// ---------------------------------------------------------------------------
// PredictiveModule R12 = R9 (142.8us, best) with latency-parallelized tail:
//  - k_reduce_x: 4 threads/column (contiguous g-slices + LDS combine),
//    grid N/64 (64 blocks): per-thread chain 128 -> 32 loads.
//  - k_finalize: 4 threads/column, grid D/64 (256 blocks): chain 32 -> 8.
// mv kernels byte-identical to R9 (TR=8 x 1KB wave-private LDS double
// buffers via global_load_lds, s_waitcnt vmcnt(8), ReLU row-skip with
// order-preserving ballot compaction). Ledger: persistent-fusion X,
// prologue-fusion X (R10 +5us), atomic-y X (R11 +20us).
//
// Numerics: f64 accumulation; f32 rounding only at sample = f32(am)+0.05f*n;
// top-k radix-select with ties stable by ascending index. Sum-order changes
// in the tail perturb ~1e-13 vs ~3e-5 top-k order-statistic gaps.
// ---------------------------------------------------------------------------

constexpr int D = 16384;
constexpr int H = 4096;

__device__ __forceinline__ void stage16(const float* g, const float* l) {
    __builtin_amdgcn_global_load_lds(
        (const __attribute__((address_space(1))) unsigned int*)g,
        (__attribute__((address_space(3))) unsigned int*)l,
        16, 0, 0);
}

__device__ __forceinline__ double wredsum(double v) {
    #pragma unroll
    for (int o = 32; o > 0; o >>= 1) v += __shfl_down(v, o, 64);
    return v;
}

// Split-K matvec (R9-proven, unchanged): grid (N/1024, K/KC). 256 thr/4
// waves; wave w owns cols [bx*1024+w*256, +256). SPARSE: ballot-compact
// nonzero rows of xd and stage only those. Writes f64 partials ypart[by][N].
template<int KC, bool SPARSE>
__global__ __launch_bounds__(256) void k_mv(
    const float* __restrict__ W, int N,
    const float* __restrict__ xf,      // !SPARSE: dense f32 x (mv1: ct)
    const double* __restrict__ xd,     // SPARSE: dense f64 relu'd x
    double* __restrict__ ypart)
{
    constexpr int NWC = (KC + 63) / 64;
    __shared__ float wbuf[4][2][8][256];   // 64 KB wave-private double buffers
    __shared__ double xv[KC];
    __shared__ int cidx[KC];
    __shared__ int wtot[NWC > 0 ? NWC : 1];
    __shared__ int s_nt;

    const int t = threadIdx.x, lane = t & 63, w = t >> 6;
    const int k0 = blockIdx.y * KC;

    if constexpr (!SPARSE) {
        if (t < KC) { xv[t] = (double)xf[k0 + t]; cidx[t] = t; }
        if (t == 0) s_nt = KC / 8;
    } else {
        double x = 0.0; bool pred = false;
        if (t < KC) { x = xd[k0 + t]; pred = x > 0.0; }
        const unsigned long long mask = __ballot(pred);
        const int rank = __popcll(mask & ((1ull << lane) - 1ull));
        const int tot  = __popcll(mask);
        if (t < KC && lane == 0) wtot[t >> 6] = tot;
        __syncthreads();
        int woffs = 0;
        #pragma unroll
        for (int ww = 0; ww < NWC; ++ww)
            if (ww < (t >> 6)) woffs += wtot[ww];
        if (pred) { cidx[woffs + rank] = t; xv[woffs + rank] = x; }
        int m = 0;
        #pragma unroll
        for (int ww = 0; ww < NWC; ++ww) m += wtot[ww];
        const int m8 = (m + 7) & ~7;
        __syncthreads();
        if (t >= m && t < m8) { cidx[t] = 0; xv[t] = 0.0; }
        if (t == 0) s_nt = m8 / 8;
    }
    __syncthreads();
    const int nt = s_nt;

    const int cbase = blockIdx.x * 1024 + w * 256;
    const float* Wg = W + (size_t)k0 * N + cbase + lane * 4;
    float* b0 = &wbuf[w][0][0][0];
    float* b1 = &wbuf[w][1][0][0];
    double a0 = 0, a1 = 0, a2 = 0, a3 = 0;

    if (nt > 0) {
        #pragma unroll
        for (int r = 0; r < 8; ++r)                     // stage tile 0
            stage16(Wg + (size_t)cidx[r] * N, b0 + r * 256);

        for (int tt = 0; tt < nt; ++tt) {
            if (tt + 1 < nt) {
                const int j = (tt + 1) * 8;
                #pragma unroll
                for (int r = 0; r < 8; ++r)             // stage tile tt+1
                    stage16(Wg + (size_t)cidx[j + r] * N, b1 + r * 256);
                asm volatile("s_waitcnt vmcnt(8)" ::: "memory");  // tt landed
            } else {
                asm volatile("s_waitcnt vmcnt(0)" ::: "memory");
            }
            #pragma unroll
            for (int r = 0; r < 8; ++r) {               // consume tile tt
                const float4 wv = *reinterpret_cast<const float4*>(b0 + r * 256 + lane * 4);
                const double x = xv[tt * 8 + r];
                a0 += x * (double)wv.x; a1 += x * (double)wv.y;
                a2 += x * (double)wv.z; a3 += x * (double)wv.w;
            }
            float* tmp = b0; b0 = b1; b1 = tmp;
        }
    }

    double* yp = ypart + (size_t)blockIdx.y * N + cbase + lane * 4;
    *reinterpret_cast<double2*>(yp + 0) = make_double2(a0, a1);
    *reinterpret_cast<double2*>(yp + 2) = make_double2(a2, a3);
}

// x[c] = relu(bias[c] + sum_g part[g][c]); grid N/64, 256 thr = 4 g-slices
// per column (contiguous ranges, ascending combine).
__global__ __launch_bounds__(256) void k_reduce_x(
    const double* __restrict__ part, int G, int N,
    const float* __restrict__ bias, double* __restrict__ xout)
{
    __shared__ double red[256];
    const int t = threadIdx.x;
    const int c = blockIdx.x * 64 + (t & 63);
    const int sl = t >> 6;
    const int gps = G / 4;
    double s = 0.0;
    #pragma unroll 8
    for (int g = sl * gps; g < (sl + 1) * gps; ++g)
        s += part[(size_t)g * N + c];
    red[t] = s;
    __syncthreads();
    if (t < 64) {
        const double tot = (double)bias[c] + red[t] + red[64 + t]
                         + red[128 + t] + red[192 + t];
        xout[c] = tot > 0.0 ? tot : 0.0;
    }
}

// Reduce p3 (G=32) + gate/clip/sample + per-block logprob partial.
// grid D/64 (256 blocks), 256 thr = 4 g-slices of 8 per column.
__global__ __launch_bounds__(256) void k_finalize(
    const double* __restrict__ p3, int G,
    const float* __restrict__ b3,
    const float* __restrict__ qm,
    const float* __restrict__ ct,
    const float* __restrict__ noise,
    float* __restrict__ samp,
    double* __restrict__ lpp)
{
    __shared__ double red[256];
    const int t = threadIdx.x;
    const int c = blockIdx.x * 64 + (t & 63);
    const int sl = t >> 6;
    const int gps = G / 4;                         // 8
    double s = 0.0;
    #pragma unroll 8
    for (int g = sl * gps; g < (sl + 1) * gps; ++g)
        s += p3[(size_t)g * D + c];
    red[t] = s;
    __syncthreads();
    if (t < 64) {
        double vm = (double)b3[c] + red[t] + red[64 + t]
                  + red[128 + t] + red[192 + t];
        vm = vm > 100.0 ? 100.0 : (vm < -100.0 ? -100.0 : vm);
        const double z = (double)qm[c] * (double)ct[c];
        const double g = 1.0 / (1.0 + exp(-z));
        double am = g * vm;                        // influence == 1.0
        am = am > 1000.0 ? 1000.0 : (am < -1000.0 ? -1000.0 : am);
        const float amf = (float)am;
        const float sp = amf + 0.05f * noise[c];
        samp[c] = sp;
        const float df = (sp - amf) / 0.05f;
        double term = (double)df * (double)df;
        term = wredsum(term);                      // t<64 == wave 0
        if (t == 0) lpp[blockIdx.x] = term;
    }
}

// Single-block radix-select top-k (stable ties by index) + final writes.
#define TPK 1024
__global__ __launch_bounds__(TPK) void k_topk(
    const float* __restrict__ samp,
    const int* __restrict__ kptr,
    const double* __restrict__ lpp, int GLP,
    float* __restrict__ out)
{
    __shared__ unsigned int u[16384];
    __shared__ int whist[16][257];
    __shared__ int hist[256];
    __shared__ int sfx[256];
    __shared__ int wsum[16];
    __shared__ int wcnt[4];
    __shared__ unsigned int s_prefix;
    __shared__ int s_kk;

    const int t = threadIdx.x;
    const int lane = t & 63, wid = t >> 6;

    for (int i = t; i < D; i += TPK)
        u[i] = __float_as_uint(samp[i]) & 0x7fffffffu;
    __syncthreads();

    const int k = *kptr;
    unsigned int prefix = 0;
    int kk = k;
    for (int pass = 0; pass < 4; ++pass) {
        const int shift = 24 - 8 * pass;
        const unsigned int dm = pass ? (0xffffffffu << (32 - 8 * pass)) : 0u;
        for (int i = t; i < 16 * 257; i += TPK) (&whist[0][0])[i] = 0;
        __syncthreads();
        for (int i = t; i < D; i += TPK) {
            const unsigned int v = u[i];
            if ((v & dm) == prefix)
                atomicAdd(&whist[wid][(v >> shift) & 0xff], 1);
        }
        __syncthreads();
        if (t < 256) {
            int s = 0;
            #pragma unroll
            for (int w = 0; w < 16; ++w) s += whist[w][t];
            hist[t] = s;
            sfx[t] = s;
        }
        __syncthreads();
        #pragma unroll
        for (int off = 1; off < 256; off <<= 1) {
            int add = 0;
            if (t < 256 && t + off < 256) add = sfx[t + off];
            __syncthreads();
            if (t < 256) sfx[t] += add;
            __syncthreads();
        }
        const bool cond = (t < 256) && (sfx[t] >= kk);
        const unsigned long long m = __ballot(cond);
        if (lane == 0 && wid < 4) wcnt[wid] = __popcll(m);
        __syncthreads();
        if (t == 0) {
            const int bs = wcnt[0] + wcnt[1] + wcnt[2] + wcnt[3] - 1;
            s_kk = kk - (sfx[bs] - hist[bs]);
            s_prefix = prefix | ((unsigned int)bs << shift);
        }
        __syncthreads();
        prefix = s_prefix;
        kk = s_kk;
        __syncthreads();
    }
    const unsigned int vstar = prefix;
    const int need = kk;

    constexpr int PER = D / TPK;  // 16
    const int base = t * PER;
    float vals[PER];
    unsigned int keys[PER];
    int cnt = 0;
    #pragma unroll
    for (int j = 0; j < PER; ++j) {
        const float f = samp[base + j];
        vals[j] = f;
        keys[j] = __float_as_uint(f) & 0x7fffffffu;
        cnt += (keys[j] == vstar) ? 1 : 0;
    }
    int inc = cnt;
    #pragma unroll
    for (int o = 1; o < 64; o <<= 1) {
        const int n = __shfl_up(inc, o, 64);
        if (lane >= o) inc += n;
    }
    if (lane == 63) wsum[wid] = inc;
    __syncthreads();
    int woff = 0;
    for (int w = 0; w < wid; ++w) woff += wsum[w];
    int offset = woff + inc - cnt;
    #pragma unroll
    for (int j = 0; j < PER; ++j) {
        float o2 = 0.0f;
        if (keys[j] > vstar) {
            o2 = vals[j];
        } else if (keys[j] == vstar) {
            if (offset < need) o2 = vals[j];
            offset++;
        }
        out[base + j] = o2;
    }

    if (wid == 0) {
        double s = 0;
        for (int g = lane; g < GLP; g += 64) s += lpp[g];
        s = wredsum(s);
        if (lane == 0) {
            const double c = -log(0.05) - 0.5 * log(2.0 * 3.14159265358979323846);
            out[D] = (float)(-0.5 * s + (double)D * c);
        }
    }
}

extern "C" void kernel_launch(void* const* d_in, const int* in_sizes, int n_in,
                              void* d_out, int out_size, void* d_ws, size_t ws_size,
                              hipStream_t stream) {
    const float* ct    = (const float*)d_in[0];
    const float* W1    = (const float*)d_in[1];
    const float* b1    = (const float*)d_in[2];
    const float* W2    = (const float*)d_in[3];
    const float* b2    = (const float*)d_in[4];
    const float* W3    = (const float*)d_in[5];
    const float* b3    = (const float*)d_in[6];
    const float* qm    = (const float*)d_in[7];
    const float* noise = (const float*)d_in[8];
    const int*   kp    = (const int*)d_in[9];

    // R9 geometry: 512-block matvec grids (2 blocks/CU at ~66KB LDS)
    constexpr int KC1 = 128, KC2 = 32, KC3 = 128;
    constexpr int G1 = D / KC1;   // 128
    constexpr int G2 = H / KC2;   // 128
    constexpr int G3 = H / KC3;   // 32
    constexpr int GLP = D / 64;   // 256 finalize blocks

    // ws: p1[128][4096] | p2[128][4096] | p3[32][16384] | x2[H] | x3[H] |
    //     samp[D] f32 | lpp[GLP]
    double* p1   = (double*)d_ws;
    double* p2   = p1 + (size_t)G1 * H;
    double* p3   = p2 + (size_t)G2 * H;
    double* x2   = p3 + (size_t)G3 * D;
    double* x3   = x2 + H;
    float*  samp = (float*)(x3 + H);
    double* lpp  = (double*)(samp + D);

    k_mv<KC1, false><<<dim3(H / 1024, G1), 256, 0, stream>>>(W1, H, ct, nullptr, p1);
    k_reduce_x<<<dim3(H / 64), 256, 0, stream>>>(p1, G1, H, b1, x2);
    k_mv<KC2, true><<<dim3(H / 1024, G2), 256, 0, stream>>>(W2, H, nullptr, x2, p2);
    k_reduce_x<<<dim3(H / 64), 256, 0, stream>>>(p2, G2, H, b2, x3);
    k_mv<KC3, true><<<dim3(D / 1024, G3), 256, 0, stream>>>(W3, D, nullptr, x3, p3);
    k_finalize<<<dim3(D / 64), 256, 0, stream>>>(p3, G3, b3, qm, ct, noise, samp, lpp);
    k_topk<<<dim3(1), TPK, 0, stream>>>(samp, kp, lpp, GLP, (float*)d_out);
}

// Round 13
// 136.131 us; speedup vs baseline: 1.1979x; 1.0053x over previous
//
#include <hip/hip_runtime.h>
#include <math.h>

// ---------------------------------------------------------------------------
// PredictiveModule R13 = R12 (136.8us, best) with a 4-deep matvec pipeline.
//
// Depth model: sustained in-flight per wave while waiting governs matvec BW
// (R6 2-deep x TR8 = 8KB good; R7/R10 decomposition: 2-deep x TR4 = 4KB cost
// +4us). R13: TR=4 rows x 1KB tiles, FOUR wave-private LDS buffers (named
// rotating pointers, no runtime indexing), prologue stages 3 tiles, loop
// stages tile tt+3 then waits vmcnt(12) (= 3 tiles x 4 loads in flight,
// tile tt landed). Sustained 12KB/wave vs 8KB. Same 2-blocks/CU geometry
// (64KB wbuf + ~2KB per block).
//
// Everything else identical to R12: ReLU row-skip (order-preserving ballot
// compaction, pad to 4), parallel reduce/finalize tail, single-block
// radix-select top-k with stable ties.
//
// Numerics: f64 accumulation; f32 rounding only at sample = f32(am)+0.05f*n.
// ---------------------------------------------------------------------------

constexpr int D = 16384;
constexpr int H = 4096;

__device__ __forceinline__ void stage16(const float* g, const float* l) {
    __builtin_amdgcn_global_load_lds(
        (const __attribute__((address_space(1))) unsigned int*)g,
        (__attribute__((address_space(3))) unsigned int*)l,
        16, 0, 0);
}

__device__ __forceinline__ double wredsum(double v) {
    #pragma unroll
    for (int o = 32; o > 0; o >>= 1) v += __shfl_down(v, o, 64);
    return v;
}

// Split-K matvec: grid (N/1024, K/KC). 256 thr / 4 waves; wave w owns cols
// [bx*1024 + w*256, +256). SPARSE: ballot-compact nonzero rows of xd, stage
// only those. 4-deep pipeline, TR=4. Writes f64 partials ypart[by][N].
template<int KC, bool SPARSE>
__global__ __launch_bounds__(256) void k_mv(
    const float* __restrict__ W, int N,
    const float* __restrict__ xf,      // !SPARSE: dense f32 x (mv1: ct)
    const double* __restrict__ xd,     // SPARSE: dense f64 relu'd x
    double* __restrict__ ypart)
{
    constexpr int NWC = (KC + 63) / 64;
    __shared__ float wbuf[4][4][4][256];   // [wave][buf][row][col] = 64 KB
    __shared__ double xv[KC];
    __shared__ int cidx[KC];
    __shared__ int wtot[NWC > 0 ? NWC : 1];
    __shared__ int s_nt;

    const int t = threadIdx.x, lane = t & 63, w = t >> 6;
    const int k0 = blockIdx.y * KC;

    if constexpr (!SPARSE) {
        if (t < KC) { xv[t] = (double)xf[k0 + t]; cidx[t] = t; }
        if (t == 0) s_nt = KC / 4;
    } else {
        double x = 0.0; bool pred = false;
        if (t < KC) { x = xd[k0 + t]; pred = x > 0.0; }
        const unsigned long long mask = __ballot(pred);
        const int rank = __popcll(mask & ((1ull << lane) - 1ull));
        const int tot  = __popcll(mask);
        if (t < KC && lane == 0) wtot[t >> 6] = tot;
        __syncthreads();
        int woffs = 0;
        #pragma unroll
        for (int ww = 0; ww < NWC; ++ww)
            if (ww < (t >> 6)) woffs += wtot[ww];
        if (pred) { cidx[woffs + rank] = t; xv[woffs + rank] = x; }
        int m = 0;
        #pragma unroll
        for (int ww = 0; ww < NWC; ++ww) m += wtot[ww];
        const int m4 = (m + 3) & ~3;
        __syncthreads();                    // compacted writes visible
        if (t >= m && t < m4) { cidx[t] = 0; xv[t] = 0.0; }  // pad (x=0)
        if (t == 0) s_nt = m4 / 4;
    }
    __syncthreads();
    const int nt = s_nt;

    const int cbase = blockIdx.x * 1024 + w * 256;
    const float* Wg = W + (size_t)k0 * N + cbase + lane * 4;
    float* q0 = &wbuf[w][0][0][0];
    float* q1 = &wbuf[w][1][0][0];
    float* q2 = &wbuf[w][2][0][0];
    float* q3 = &wbuf[w][3][0][0];
    double a0 = 0, a1 = 0, a2 = 0, a3 = 0;

    if (nt > 0) {
        // prologue: stage up to 3 tiles
        #pragma unroll
        for (int r = 0; r < 4; ++r)
            stage16(Wg + (size_t)cidx[r] * N, q0 + r * 256);
        if (nt > 1) {
            #pragma unroll
            for (int r = 0; r < 4; ++r)
                stage16(Wg + (size_t)cidx[4 + r] * N, q1 + r * 256);
        }
        if (nt > 2) {
            #pragma unroll
            for (int r = 0; r < 4; ++r)
                stage16(Wg + (size_t)cidx[8 + r] * N, q2 + r * 256);
        }

        for (int tt = 0; tt < nt; ++tt) {
            if (tt + 3 < nt) {
                const int j = (tt + 3) * 4;
                #pragma unroll
                for (int r = 0; r < 4; ++r)             // stage tile tt+3
                    stage16(Wg + (size_t)cidx[j + r] * N, q3 + r * 256);
                asm volatile("s_waitcnt vmcnt(12)" ::: "memory");  // tt landed
            } else {
                const int rem = nt - 1 - tt;            // block-uniform
                if (rem >= 2)      asm volatile("s_waitcnt vmcnt(8)" ::: "memory");
                else if (rem == 1) asm volatile("s_waitcnt vmcnt(4)" ::: "memory");
                else               asm volatile("s_waitcnt vmcnt(0)" ::: "memory");
            }
            #pragma unroll
            for (int r = 0; r < 4; ++r) {               // consume tile tt
                const float4 wv = *reinterpret_cast<const float4*>(q0 + r * 256 + lane * 4);
                const double x = xv[tt * 4 + r];
                a0 += x * (double)wv.x; a1 += x * (double)wv.y;
                a2 += x * (double)wv.z; a3 += x * (double)wv.w;
            }
            float* tmp = q0; q0 = q1; q1 = q2; q2 = q3; q3 = tmp;  // rotate
        }
    }

    double* yp = ypart + (size_t)blockIdx.y * N + cbase + lane * 4;
    *reinterpret_cast<double2*>(yp + 0) = make_double2(a0, a1);
    *reinterpret_cast<double2*>(yp + 2) = make_double2(a2, a3);
}

// x[c] = relu(bias[c] + sum_g part[g][c]); grid N/64, 256 thr = 4 g-slices
// per column (contiguous ranges, ascending combine).
__global__ __launch_bounds__(256) void k_reduce_x(
    const double* __restrict__ part, int G, int N,
    const float* __restrict__ bias, double* __restrict__ xout)
{
    __shared__ double red[256];
    const int t = threadIdx.x;
    const int c = blockIdx.x * 64 + (t & 63);
    const int sl = t >> 6;
    const int gps = G / 4;
    double s = 0.0;
    #pragma unroll 8
    for (int g = sl * gps; g < (sl + 1) * gps; ++g)
        s += part[(size_t)g * N + c];
    red[t] = s;
    __syncthreads();
    if (t < 64) {
        const double tot = (double)bias[c] + red[t] + red[64 + t]
                         + red[128 + t] + red[192 + t];
        xout[c] = tot > 0.0 ? tot : 0.0;
    }
}

// Reduce p3 (G=32) + gate/clip/sample + per-block logprob partial.
// grid D/64 (256 blocks), 256 thr = 4 g-slices of 8 per column.
__global__ __launch_bounds__(256) void k_finalize(
    const double* __restrict__ p3, int G,
    const float* __restrict__ b3,
    const float* __restrict__ qm,
    const float* __restrict__ ct,
    const float* __restrict__ noise,
    float* __restrict__ samp,
    double* __restrict__ lpp)
{
    __shared__ double red[256];
    const int t = threadIdx.x;
    const int c = blockIdx.x * 64 + (t & 63);
    const int sl = t >> 6;
    const int gps = G / 4;                         // 8
    double s = 0.0;
    #pragma unroll 8
    for (int g = sl * gps; g < (sl + 1) * gps; ++g)
        s += p3[(size_t)g * D + c];
    red[t] = s;
    __syncthreads();
    if (t < 64) {
        double vm = (double)b3[c] + red[t] + red[64 + t]
                  + red[128 + t] + red[192 + t];
        vm = vm > 100.0 ? 100.0 : (vm < -100.0 ? -100.0 : vm);
        const double z = (double)qm[c] * (double)ct[c];
        const double g = 1.0 / (1.0 + exp(-z));
        double am = g * vm;                        // influence == 1.0
        am = am > 1000.0 ? 1000.0 : (am < -1000.0 ? -1000.0 : am);
        const float amf = (float)am;
        const float sp = amf + 0.05f * noise[c];
        samp[c] = sp;
        const float df = (sp - amf) / 0.05f;
        double term = (double)df * (double)df;
        term = wredsum(term);                      // t<64 == wave 0
        if (t == 0) lpp[blockIdx.x] = term;
    }
}

// Single-block radix-select top-k (stable ties by index) + final writes.
#define TPK 1024
__global__ __launch_bounds__(TPK) void k_topk(
    const float* __restrict__ samp,
    const int* __restrict__ kptr,
    const double* __restrict__ lpp, int GLP,
    float* __restrict__ out)
{
    __shared__ unsigned int u[16384];
    __shared__ int whist[16][257];
    __shared__ int hist[256];
    __shared__ int sfx[256];
    __shared__ int wsum[16];
    __shared__ int wcnt[4];
    __shared__ unsigned int s_prefix;
    __shared__ int s_kk;

    const int t = threadIdx.x;
    const int lane = t & 63, wid = t >> 6;

    for (int i = t; i < D; i += TPK)
        u[i] = __float_as_uint(samp[i]) & 0x7fffffffu;
    __syncthreads();

    const int k = *kptr;
    unsigned int prefix = 0;
    int kk = k;
    for (int pass = 0; pass < 4; ++pass) {
        const int shift = 24 - 8 * pass;
        const unsigned int dm = pass ? (0xffffffffu << (32 - 8 * pass)) : 0u;
        for (int i = t; i < 16 * 257; i += TPK) (&whist[0][0])[i] = 0;
        __syncthreads();
        for (int i = t; i < D; i += TPK) {
            const unsigned int v = u[i];
            if ((v & dm) == prefix)
                atomicAdd(&whist[wid][(v >> shift) & 0xff], 1);
        }
        __syncthreads();
        if (t < 256) {
            int s = 0;
            #pragma unroll
            for (int w = 0; w < 16; ++w) s += whist[w][t];
            hist[t] = s;
            sfx[t] = s;
        }
        __syncthreads();
        #pragma unroll
        for (int off = 1; off < 256; off <<= 1) {
            int add = 0;
            if (t < 256 && t + off < 256) add = sfx[t + off];
            __syncthreads();
            if (t < 256) sfx[t] += add;
            __syncthreads();
        }
        const bool cond = (t < 256) && (sfx[t] >= kk);
        const unsigned long long m = __ballot(cond);
        if (lane == 0 && wid < 4) wcnt[wid] = __popcll(m);
        __syncthreads();
        if (t == 0) {
            const int bs = wcnt[0] + wcnt[1] + wcnt[2] + wcnt[3] - 1;
            s_kk = kk - (sfx[bs] - hist[bs]);
            s_prefix = prefix | ((unsigned int)bs << shift);
        }
        __syncthreads();
        prefix = s_prefix;
        kk = s_kk;
        __syncthreads();
    }
    const unsigned int vstar = prefix;
    const int need = kk;

    constexpr int PER = D / TPK;  // 16
    const int base = t * PER;
    float vals[PER];
    unsigned int keys[PER];
    int cnt = 0;
    #pragma unroll
    for (int j = 0; j < PER; ++j) {
        const float f = samp[base + j];
        vals[j] = f;
        keys[j] = __float_as_uint(f) & 0x7fffffffu;
        cnt += (keys[j] == vstar) ? 1 : 0;
    }
    int inc = cnt;
    #pragma unroll
    for (int o = 1; o < 64; o <<= 1) {
        const int n = __shfl_up(inc, o, 64);
        if (lane >= o) inc += n;
    }
    if (lane == 63) wsum[wid] = inc;
    __syncthreads();
    int woff = 0;
    for (int w = 0; w < wid; ++w) woff += wsum[w];
    int offset = woff + inc - cnt;
    #pragma unroll
    for (int j = 0; j < PER; ++j) {
        float o2 = 0.0f;
        if (keys[j] > vstar) {
            o2 = vals[j];
        } else if (keys[j] == vstar) {
            if (offset < need) o2 = vals[j];
            offset++;
        }
        out[base + j] = o2;
    }

    if (wid == 0) {
        double s = 0;
        for (int g = lane; g < GLP; g += 64) s += lpp[g];
        s = wredsum(s);
        if (lane == 0) {
            const double c = -log(0.05) - 0.5 * log(2.0 * 3.14159265358979323846);
            out[D] = (float)(-0.5 * s + (double)D * c);
        }
    }
}

extern "C" void kernel_launch(void* const* d_in, const int* in_sizes, int n_in,
                              void* d_out, int out_size, void* d_ws, size_t ws_size,
                              hipStream_t stream) {
    const float* ct    = (const float*)d_in[0];
    const float* W1    = (const float*)d_in[1];
    const float* b1    = (const float*)d_in[2];
    const float* W2    = (const float*)d_in[3];
    const float* b2    = (const float*)d_in[4];
    const float* W3    = (const float*)d_in[5];
    const float* b3    = (const float*)d_in[6];
    const float* qm    = (const float*)d_in[7];
    const float* noise = (const float*)d_in[8];
    const int*   kp    = (const int*)d_in[9];

    // 512-block matvec grids (2 blocks/CU at ~66KB LDS)
    constexpr int KC1 = 128, KC2 = 32, KC3 = 128;
    constexpr int G1 = D / KC1;   // 128
    constexpr int G2 = H / KC2;   // 128
    constexpr int G3 = H / KC3;   // 32
    constexpr int GLP = D / 64;   // 256 finalize blocks

    // ws: p1[128][4096] | p2[128][4096] | p3[32][16384] | x2[H] | x3[H] |
    //     samp[D] f32 | lpp[GLP]
    double* p1   = (double*)d_ws;
    double* p2   = p1 + (size_t)G1 * H;
    double* p3   = p2 + (size_t)G2 * H;
    double* x2   = p3 + (size_t)G3 * D;
    double* x3   = x2 + H;
    float*  samp = (float*)(x3 + H);
    double* lpp  = (double*)(samp + D);

    k_mv<KC1, false><<<dim3(H / 1024, G1), 256, 0, stream>>>(W1, H, ct, nullptr, p1);
    k_reduce_x<<<dim3(H / 64), 256, 0, stream>>>(p1, G1, H, b1, x2);
    k_mv<KC2, true><<<dim3(H / 1024, G2), 256, 0, stream>>>(W2, H, nullptr, x2, p2);
    k_reduce_x<<<dim3(H / 64), 256, 0, stream>>>(p2, G2, H, b2, x3);
    k_mv<KC3, true><<<dim3(D / 1024, G3), 256, 0, stream>>>(W3, D, nullptr, x3, p3);
    k_finalize<<<dim3(D / 64), 256, 0, stream>>>(p3, G3, b3, qm, ct, noise, samp, lpp);
    k_topk<<<dim3(1), TPK, 0, stream>>>(samp, kp, lpp, GLP, (float*)d_out);
}

// Round 14
// 134.309 us; speedup vs baseline: 1.2141x; 1.0136x over previous
//
#include <hip/hip_runtime.h>
#include <math.h>

// ---------------------------------------------------------------------------
// PredictiveModule R14 = R13 (136.1us) with 2x-oversubscribed mv1/mv3 grids
// (KC 128->64, 1024 blocks, 2 resident + 2 queued per CU): queued blocks'
// ramps overlap resident blocks' steady-state; drain tails halve.
// Ledger: persistent-fusion X, prologue-fusion X, atomic-y X, reg-pipeline X,
// 4-deep depth ~neutral, row-skip OK (-32us), parallel tail OK (-6us).
// Marginal streaming BW measured 5.0 TB/s (R6->R9: 160MB saved 31.9us).
//
// mv pipeline (R13): TR=4 rows x 1KB tiles, 4 wave-private LDS buffers
// (named rotating pointers), prologue stages 3 tiles, steady-state
// s_waitcnt vmcnt(12); ReLU row-skip via order-preserving ballot compaction.
//
// Numerics: f64 accumulation; f32 rounding only at sample = f32(am)+0.05f*n;
// top-k radix-select, ties stable by ascending index.
// ---------------------------------------------------------------------------

constexpr int D = 16384;
constexpr int H = 4096;

__device__ __forceinline__ void stage16(const float* g, const float* l) {
    __builtin_amdgcn_global_load_lds(
        (const __attribute__((address_space(1))) unsigned int*)g,
        (__attribute__((address_space(3))) unsigned int*)l,
        16, 0, 0);
}

__device__ __forceinline__ double wredsum(double v) {
    #pragma unroll
    for (int o = 32; o > 0; o >>= 1) v += __shfl_down(v, o, 64);
    return v;
}

// Split-K matvec: grid (N/1024, K/KC). 256 thr / 4 waves; wave w owns cols
// [bx*1024 + w*256, +256). SPARSE: ballot-compact nonzero rows of xd, stage
// only those. 4-deep pipeline, TR=4. Writes f64 partials ypart[by][N].
template<int KC, bool SPARSE>
__global__ __launch_bounds__(256) void k_mv(
    const float* __restrict__ W, int N,
    const float* __restrict__ xf,      // !SPARSE: dense f32 x (mv1: ct)
    const double* __restrict__ xd,     // SPARSE: dense f64 relu'd x
    double* __restrict__ ypart)
{
    constexpr int NWC = (KC + 63) / 64;
    __shared__ float wbuf[4][4][4][256];   // [wave][buf][row][col] = 64 KB
    __shared__ double xv[KC];
    __shared__ int cidx[KC];
    __shared__ int wtot[NWC > 0 ? NWC : 1];
    __shared__ int s_nt;

    const int t = threadIdx.x, lane = t & 63, w = t >> 6;
    const int k0 = blockIdx.y * KC;

    if constexpr (!SPARSE) {
        if (t < KC) { xv[t] = (double)xf[k0 + t]; cidx[t] = t; }
        if (t == 0) s_nt = KC / 4;
    } else {
        double x = 0.0; bool pred = false;
        if (t < KC) { x = xd[k0 + t]; pred = x > 0.0; }
        const unsigned long long mask = __ballot(pred);
        const int rank = __popcll(mask & ((1ull << lane) - 1ull));
        const int tot  = __popcll(mask);
        if (t < KC && lane == 0) wtot[t >> 6] = tot;
        __syncthreads();
        int woffs = 0;
        #pragma unroll
        for (int ww = 0; ww < NWC; ++ww)
            if (ww < (t >> 6)) woffs += wtot[ww];
        if (pred) { cidx[woffs + rank] = t; xv[woffs + rank] = x; }
        int m = 0;
        #pragma unroll
        for (int ww = 0; ww < NWC; ++ww) m += wtot[ww];
        const int m4 = (m + 3) & ~3;
        __syncthreads();                    // compacted writes visible
        if (t >= m && t < m4) { cidx[t] = 0; xv[t] = 0.0; }  // pad (x=0)
        if (t == 0) s_nt = m4 / 4;
    }
    __syncthreads();
    const int nt = s_nt;

    const int cbase = blockIdx.x * 1024 + w * 256;
    const float* Wg = W + (size_t)k0 * N + cbase + lane * 4;
    float* q0 = &wbuf[w][0][0][0];
    float* q1 = &wbuf[w][1][0][0];
    float* q2 = &wbuf[w][2][0][0];
    float* q3 = &wbuf[w][3][0][0];
    double a0 = 0, a1 = 0, a2 = 0, a3 = 0;

    if (nt > 0) {
        // prologue: stage up to 3 tiles
        #pragma unroll
        for (int r = 0; r < 4; ++r)
            stage16(Wg + (size_t)cidx[r] * N, q0 + r * 256);
        if (nt > 1) {
            #pragma unroll
            for (int r = 0; r < 4; ++r)
                stage16(Wg + (size_t)cidx[4 + r] * N, q1 + r * 256);
        }
        if (nt > 2) {
            #pragma unroll
            for (int r = 0; r < 4; ++r)
                stage16(Wg + (size_t)cidx[8 + r] * N, q2 + r * 256);
        }

        for (int tt = 0; tt < nt; ++tt) {
            if (tt + 3 < nt) {
                const int j = (tt + 3) * 4;
                #pragma unroll
                for (int r = 0; r < 4; ++r)             // stage tile tt+3
                    stage16(Wg + (size_t)cidx[j + r] * N, q3 + r * 256);
                asm volatile("s_waitcnt vmcnt(12)" ::: "memory");  // tt landed
            } else {
                const int rem = nt - 1 - tt;            // block-uniform
                if (rem >= 2)      asm volatile("s_waitcnt vmcnt(8)" ::: "memory");
                else if (rem == 1) asm volatile("s_waitcnt vmcnt(4)" ::: "memory");
                else               asm volatile("s_waitcnt vmcnt(0)" ::: "memory");
            }
            #pragma unroll
            for (int r = 0; r < 4; ++r) {               // consume tile tt
                const float4 wv = *reinterpret_cast<const float4*>(q0 + r * 256 + lane * 4);
                const double x = xv[tt * 4 + r];
                a0 += x * (double)wv.x; a1 += x * (double)wv.y;
                a2 += x * (double)wv.z; a3 += x * (double)wv.w;
            }
            float* tmp = q0; q0 = q1; q1 = q2; q2 = q3; q3 = tmp;  // rotate
        }
    }

    double* yp = ypart + (size_t)blockIdx.y * N + cbase + lane * 4;
    *reinterpret_cast<double2*>(yp + 0) = make_double2(a0, a1);
    *reinterpret_cast<double2*>(yp + 2) = make_double2(a2, a3);
}

// x[c] = relu(bias[c] + sum_g part[g][c]); grid N/32, 256 thr = 8 g-slices
// per column (contiguous ranges, ascending combine).
__global__ __launch_bounds__(256) void k_reduce_x(
    const double* __restrict__ part, int G, int N,
    const float* __restrict__ bias, double* __restrict__ xout)
{
    __shared__ double red[256];
    const int t = threadIdx.x;
    const int c = blockIdx.x * 32 + (t & 31);
    const int sl = t >> 5;                 // 8 slices
    const int gps = G / 8;
    double s = 0.0;
    #pragma unroll 8
    for (int g = sl * gps; g < (sl + 1) * gps; ++g)
        s += part[(size_t)g * N + c];
    red[t] = s;
    __syncthreads();
    if (t < 32) {
        double tot = (double)bias[c];
        #pragma unroll
        for (int s2 = 0; s2 < 8; ++s2) tot += red[s2 * 32 + t];
        xout[c] = tot > 0.0 ? tot : 0.0;
    }
}

// Reduce p3 (G groups) + gate/clip/sample + per-block logprob partial.
// grid D/64 (256 blocks), 256 thr = 4 g-slices per column.
__global__ __launch_bounds__(256) void k_finalize(
    const double* __restrict__ p3, int G,
    const float* __restrict__ b3,
    const float* __restrict__ qm,
    const float* __restrict__ ct,
    const float* __restrict__ noise,
    float* __restrict__ samp,
    double* __restrict__ lpp)
{
    __shared__ double red[256];
    const int t = threadIdx.x;
    const int c = blockIdx.x * 64 + (t & 63);
    const int sl = t >> 6;
    const int gps = G / 4;                         // 16
    double s = 0.0;
    #pragma unroll 8
    for (int g = sl * gps; g < (sl + 1) * gps; ++g)
        s += p3[(size_t)g * D + c];
    red[t] = s;
    __syncthreads();
    if (t < 64) {
        double vm = (double)b3[c] + red[t] + red[64 + t]
                  + red[128 + t] + red[192 + t];
        vm = vm > 100.0 ? 100.0 : (vm < -100.0 ? -100.0 : vm);
        const double z = (double)qm[c] * (double)ct[c];
        const double g = 1.0 / (1.0 + exp(-z));
        double am = g * vm;                        // influence == 1.0
        am = am > 1000.0 ? 1000.0 : (am < -1000.0 ? -1000.0 : am);
        const float amf = (float)am;
        const float sp = amf + 0.05f * noise[c];
        samp[c] = sp;
        const float df = (sp - amf) / 0.05f;
        double term = (double)df * (double)df;
        term = wredsum(term);                      // t<64 == wave 0
        if (t == 0) lpp[blockIdx.x] = term;
    }
}

// Single-block radix-select top-k (stable ties by index) + final writes.
#define TPK 1024
__global__ __launch_bounds__(TPK) void k_topk(
    const float* __restrict__ samp,
    const int* __restrict__ kptr,
    const double* __restrict__ lpp, int GLP,
    float* __restrict__ out)
{
    __shared__ unsigned int u[16384];
    __shared__ int whist[16][257];
    __shared__ int hist[256];
    __shared__ int sfx[256];
    __shared__ int wsum[16];
    __shared__ int wcnt[4];
    __shared__ unsigned int s_prefix;
    __shared__ int s_kk;

    const int t = threadIdx.x;
    const int lane = t & 63, wid = t >> 6;

    for (int i = t; i < D; i += TPK)
        u[i] = __float_as_uint(samp[i]) & 0x7fffffffu;
    __syncthreads();

    const int k = *kptr;
    unsigned int prefix = 0;
    int kk = k;
    for (int pass = 0; pass < 4; ++pass) {
        const int shift = 24 - 8 * pass;
        const unsigned int dm = pass ? (0xffffffffu << (32 - 8 * pass)) : 0u;
        for (int i = t; i < 16 * 257; i += TPK) (&whist[0][0])[i] = 0;
        __syncthreads();
        for (int i = t; i < D; i += TPK) {
            const unsigned int v = u[i];
            if ((v & dm) == prefix)
                atomicAdd(&whist[wid][(v >> shift) & 0xff], 1);
        }
        __syncthreads();
        if (t < 256) {
            int s = 0;
            #pragma unroll
            for (int w = 0; w < 16; ++w) s += whist[w][t];
            hist[t] = s;
            sfx[t] = s;
        }
        __syncthreads();
        #pragma unroll
        for (int off = 1; off < 256; off <<= 1) {
            int add = 0;
            if (t < 256 && t + off < 256) add = sfx[t + off];
            __syncthreads();
            if (t < 256) sfx[t] += add;
            __syncthreads();
        }
        const bool cond = (t < 256) && (sfx[t] >= kk);
        const unsigned long long m = __ballot(cond);
        if (lane == 0 && wid < 4) wcnt[wid] = __popcll(m);
        __syncthreads();
        if (t == 0) {
            const int bs = wcnt[0] + wcnt[1] + wcnt[2] + wcnt[3] - 1;
            s_kk = kk - (sfx[bs] - hist[bs]);
            s_prefix = prefix | ((unsigned int)bs << shift);
        }
        __syncthreads();
        prefix = s_prefix;
        kk = s_kk;
        __syncthreads();
    }
    const unsigned int vstar = prefix;
    const int need = kk;

    constexpr int PER = D / TPK;  // 16
    const int base = t * PER;
    float vals[PER];
    unsigned int keys[PER];
    int cnt = 0;
    #pragma unroll
    for (int j = 0; j < PER; ++j) {
        const float f = samp[base + j];
        vals[j] = f;
        keys[j] = __float_as_uint(f) & 0x7fffffffu;
        cnt += (keys[j] == vstar) ? 1 : 0;
    }
    int inc = cnt;
    #pragma unroll
    for (int o = 1; o < 64; o <<= 1) {
        const int n = __shfl_up(inc, o, 64);
        if (lane >= o) inc += n;
    }
    if (lane == 63) wsum[wid] = inc;
    __syncthreads();
    int woff = 0;
    for (int w = 0; w < wid; ++w) woff += wsum[w];
    int offset = woff + inc - cnt;
    #pragma unroll
    for (int j = 0; j < PER; ++j) {
        float o2 = 0.0f;
        if (keys[j] > vstar) {
            o2 = vals[j];
        } else if (keys[j] == vstar) {
            if (offset < need) o2 = vals[j];
            offset++;
        }
        out[base + j] = o2;
    }

    if (wid == 0) {
        double s = 0;
        for (int g = lane; g < GLP; g += 64) s += lpp[g];
        s = wredsum(s);
        if (lane == 0) {
            const double c = -log(0.05) - 0.5 * log(2.0 * 3.14159265358979323846);
            out[D] = (float)(-0.5 * s + (double)D * c);
        }
    }
}

extern "C" void kernel_launch(void* const* d_in, const int* in_sizes, int n_in,
                              void* d_out, int out_size, void* d_ws, size_t ws_size,
                              hipStream_t stream) {
    const float* ct    = (const float*)d_in[0];
    const float* W1    = (const float*)d_in[1];
    const float* b1    = (const float*)d_in[2];
    const float* W2    = (const float*)d_in[3];
    const float* b2    = (const float*)d_in[4];
    const float* W3    = (const float*)d_in[5];
    const float* b3    = (const float*)d_in[6];
    const float* qm    = (const float*)d_in[7];
    const float* noise = (const float*)d_in[8];
    const int*   kp    = (const int*)d_in[9];

    // Oversubscribed mv grids: mv1/mv3 1024 blocks (2 resident + 2 queued
    // per CU), mv2 512 blocks (KC=32 keeps its pipeline from starving).
    constexpr int KC1 = 64, KC2 = 32, KC3 = 64;
    constexpr int G1 = D / KC1;   // 256
    constexpr int G2 = H / KC2;   // 128
    constexpr int G3 = H / KC3;   // 64
    constexpr int GLP = D / 64;   // 256 finalize blocks

    // ws: p1[256][4096] | p2[128][4096] | p3[64][16384] | x2[H] | x3[H] |
    //     samp[D] f32 | lpp[GLP]
    double* p1   = (double*)d_ws;
    double* p2   = p1 + (size_t)G1 * H;
    double* p3   = p2 + (size_t)G2 * H;
    double* x2   = p3 + (size_t)G3 * D;
    double* x3   = x2 + H;
    float*  samp = (float*)(x3 + H);
    double* lpp  = (double*)(samp + D);

    k_mv<KC1, false><<<dim3(H / 1024, G1), 256, 0, stream>>>(W1, H, ct, nullptr, p1);
    k_reduce_x<<<dim3(H / 32), 256, 0, stream>>>(p1, G1, H, b1, x2);
    k_mv<KC2, true><<<dim3(H / 1024, G2), 256, 0, stream>>>(W2, H, nullptr, x2, p2);
    k_reduce_x<<<dim3(H / 32), 256, 0, stream>>>(p2, G2, H, b2, x3);
    k_mv<KC3, true><<<dim3(D / 1024, G3), 256, 0, stream>>>(W3, D, nullptr, x3, p3);
    k_finalize<<<dim3(D / 64), 256, 0, stream>>>(p3, G3, b3, qm, ct, noise, samp, lpp);
    k_topk<<<dim3(1), TPK, 0, stream>>>(samp, kp, lpp, GLP, (float*)d_out);
}